// Round 1
// baseline (100.799 us; speedup 1.0000x reference)
//
#include <hip/hip_runtime.h>

#define BB 4
#define CC 64
#define HH 64
#define WW 64
#define PATCH 9
#define HALF 4
#define P2 81
#define CHUNK 16
#define HW (HH * WW)

// -------- Kernel 1: inverse L2 norms for both features --------
// invn layout in ws: [2][B][H][W] floats
__global__ __launch_bounds__(512) void norm_kernel(const float* __restrict__ f1,
                                                   const float* __restrict__ f2,
                                                   float* __restrict__ invn) {
    int p = blockIdx.x * blockDim.x + threadIdx.x;   // 0..32767
    int feat = p >> 14;            // 0: f1, 1: f2 (wave-uniform: block-uniform)
    int idx = p & 16383;           // b*4096 + y*64 + x
    int b = idx >> 12;
    int sp = idx & 4095;
    const float* src = feat ? f2 : f1;
    const float* base = src + b * (CC * HW) + sp;
    float s = 0.f;
#pragma unroll
    for (int c = 0; c < CC; ++c) {
        float v = base[c * HW];
        s += v * v;
    }
    invn[p] = rsqrtf(s + 1e-6f);
}

// -------- Kernel 2: correlation + ReLU --------
// block = (b,y) row; 576 threads = (x in 0..63, dy in 0..8)
// acc[dx] over 9 dx; channels chunked through LDS.
__global__ __launch_bounds__(576) void corr_kernel(const float* __restrict__ f1,
                                                   const float* __restrict__ f2,
                                                   const float* __restrict__ invn,
                                                   float* __restrict__ out) {
    __shared__ float ldsA[CHUNK * WW];                 // [cc][x]        4 KB
    __shared__ float ldsB[CHUNK * PATCH * (WW + 8)];   // [cc][r][xx]   41.5 KB

    const int tid = threadIdx.x;
    const int x = tid & 63;
    const int dy = tid >> 6;          // 0..8
    const int bid = blockIdx.x;
    const int b = bid >> 6;
    const int y = bid & 63;

    const float* f1b = f1 + b * CC * HW;
    const float* f2b = f2 + b * CC * HW;
    const float* in1 = invn + b * HW;
    const float* in2 = invn + BB * HW + b * HW;

    float acc[PATCH];
#pragma unroll
    for (int i = 0; i < PATCH; ++i) acc[i] = 0.f;

    for (int c0 = 0; c0 < CC; c0 += CHUNK) {
        __syncthreads();
        // stage f1 row chunk (pre-scaled by inv-norm)
        for (int i = tid; i < CHUNK * WW; i += 576) {
            int cc = i >> 6;
            int xx = i & 63;
            ldsA[i] = f1b[(c0 + cc) * HW + y * WW + xx] * in1[y * WW + xx];
        }
        // stage f2 halo chunk: rows y-4..y+4, cols -4..67, zero-padded, pre-scaled
        for (int i = tid; i < CHUNK * PATCH * 72; i += 576) {
            int cc = i / 648;
            int rem = i - cc * 648;
            int r = rem / 72;
            int xx = rem - r * 72;
            int grow = y + r - HALF;
            int gcol = xx - HALF;
            float v = 0.f;
            if ((unsigned)grow < HH && (unsigned)gcol < WW) {
                int off = grow * WW + gcol;
                v = f2b[(c0 + cc) * HW + off] * in2[off];
            }
            ldsB[i] = v;
        }
        __syncthreads();
#pragma unroll
        for (int cc = 0; cc < CHUNK; ++cc) {
            float a = ldsA[cc * WW + x];
            const float* brow = &ldsB[(cc * PATCH + dy) * 72 + x];
#pragma unroll
            for (int dx = 0; dx < PATCH; ++dx)
                acc[dx] += a * brow[dx];
        }
    }

    // out[b][dy*9+dx][y*64+x], ReLU
    float* ob = out + b * P2 * HW + y * WW + x;
#pragma unroll
    for (int dx = 0; dx < PATCH; ++dx)
        ob[(dy * PATCH + dx) * HW] = fmaxf(acc[dx], 0.f);
}

extern "C" void kernel_launch(void* const* d_in, const int* in_sizes, int n_in,
                              void* d_out, int out_size, void* d_ws, size_t ws_size,
                              hipStream_t stream) {
    const float* f1 = (const float*)d_in[0];
    const float* f2 = (const float*)d_in[1];
    float* out = (float*)d_out;
    float* invn = (float*)d_ws;   // 2*B*H*W floats = 128 KB

    norm_kernel<<<64, 512, 0, stream>>>(f1, f2, invn);
    corr_kernel<<<BB * HH, 576, 0, stream>>>(f1, f2, invn, out);
}

// Round 3
// 72.755 us; speedup vs baseline: 1.3855x; 1.3855x over previous
//
#include <hip/hip_runtime.h>

#define BB 4
#define CC 64
#define HH 64
#define WW 64
#define PATCH 9
#define HALF 4
#define P2 81
#define HW (HH * WW)

// -------- Kernel 1: inverse L2 norms for both features --------
// invn layout in ws: [2][B][H][W] floats
__global__ __launch_bounds__(128) void norm_kernel(const float* __restrict__ f1,
                                                   const float* __restrict__ f2,
                                                   float* __restrict__ invn) {
    int p = blockIdx.x * 128 + threadIdx.x;   // 0..32767
    int feat = p >> 14;            // 0: f1, 1: f2 (block-uniform)
    int idx = p & 16383;           // b*4096 + y*64 + x
    const float* base = (feat ? f2 : f1) + (idx >> 12) * (CC * HW) + (idx & 4095);
    float s = 0.f;
#pragma unroll
    for (int c = 0; c < CC; ++c) {
        float v = base[c * HW];
        s += v * v;
    }
    invn[p] = rsqrtf(s + 1e-6f);
}

// -------- Kernel 2: correlation + ReLU --------
// One block per (b, y, dy): 2304 blocks. 192 threads = (x:64, dx-group:3),
// each thread computes 3 consecutive dx taps.
// Normalization factored out: out = relu(raw_dot * invn1[y,x] * invn2[y2,x2]).
__global__ __launch_bounds__(192) void corr_kernel(const float* __restrict__ f1,
                                                   const float* __restrict__ f2,
                                                   const float* __restrict__ invn,
                                                   float* __restrict__ out) {
    __shared__ float ldsB[CC * 72];   // [c][72]: cols 0..3 & 68..71 are zero pad (18.4 KB)

    const int tid = threadIdx.x;
    const int bid = blockIdx.x;
    const int dy = bid % PATCH;          // fastest -> consecutive blocks share f1/f2 rows
    const int y  = (bid / PATCH) & 63;
    const int b  = bid / (PATCH * HH);
    const int x  = tid & 63;
    const int g  = tid >> 6;             // 0..2 (dx group)
    const int gy2 = y + dy - HALF;

    float* ob = out + b * P2 * HW + y * WW + x;

    if ((unsigned)gy2 >= HH) {
        // whole dy-row out of bounds -> zeros
#pragma unroll
        for (int j = 0; j < 3; ++j)
            ob[(dy * PATCH + g * 3 + j) * HW] = 0.f;
        return;
    }

    const float* f1r = f1 + b * CC * HW + y * WW;     // + c*HW + x
    const float* f2r = f2 + b * CC * HW + gy2 * WW;   // + c*HW

    // stage raw f2 row (all channels) as [c][72] with zero pads, float4 loads
    // data occupies padded cols 4..67; pads are cols 0..3 and 68..71 (disjoint)
    for (int i = tid; i < CC * 16; i += 192) {
        int c = i >> 4, k = i & 15;
        float4 v = *(const float4*)(f2r + c * HW + k * 4);
        *(float4*)(&ldsB[c * 72 + 4 + k * 4]) = v;
    }
    for (int j = tid; j < CC * 8; j += 192) {
        int c = j >> 3, e = j & 7;
        ldsB[c * 72 + (e < 4 ? e : e + 64)] = 0.f;   // 0..3 and 68..71
    }
    __syncthreads();

    float acc0 = 0.f, acc1 = 0.f, acc2 = 0.f;
    const int boff = x + g * 3;   // padded-col of tap0: x + (g*3+j) - HALF + 4 = boff + j
#pragma unroll
    for (int c0 = 0; c0 < CC; c0 += 16) {
        float a[16];
#pragma unroll
        for (int j = 0; j < 16; ++j) a[j] = f1r[(c0 + j) * HW + x];
#pragma unroll
        for (int j = 0; j < 16; ++j) {
            const float* br = &ldsB[(c0 + j) * 72 + boff];
            acc0 = fmaf(a[j], br[0], acc0);
            acc1 = fmaf(a[j], br[1], acc1);
            acc2 = fmaf(a[j], br[2], acc2);
        }
    }

    const float s1 = invn[b * HW + y * WW + x];
    const float* in2 = invn + BB * HW + b * HW + gy2 * WW;
    float accs[3] = {acc0, acc1, acc2};
#pragma unroll
    for (int j = 0; j < 3; ++j) {
        int dx = g * 3 + j;
        int xx = x + dx - HALF;
        xx = min(max(xx, 0), WW - 1);      // OOB taps have acc==0 (pad), clamp for safety
        float s2 = in2[xx];
        ob[(dy * PATCH + dx) * HW] = fmaxf(accs[j] * s1 * s2, 0.f);
    }
}

extern "C" void kernel_launch(void* const* d_in, const int* in_sizes, int n_in,
                              void* d_out, int out_size, void* d_ws, size_t ws_size,
                              hipStream_t stream) {
    const float* f1 = (const float*)d_in[0];
    const float* f2 = (const float*)d_in[1];
    float* out = (float*)d_out;
    float* invn = (float*)d_ws;   // 2*B*H*W floats = 128 KB

    norm_kernel<<<256, 128, 0, stream>>>(f1, f2, invn);
    corr_kernel<<<BB * HH * PATCH, 192, 0, stream>>>(f1, f2, invn, out);
}

// Round 4
// 70.723 us; speedup vs baseline: 1.4253x; 1.0287x over previous
//
#include <hip/hip_runtime.h>

#define BB 4
#define CC 64
#define HH 64
#define WW 64
#define PATCH 9
#define HALF 4
#define P2 81
#define HW (HH * WW)

typedef float v2f __attribute__((ext_vector_type(2)));

// Fused: L2-norm factors + 9x9 correlation + ReLU, single kernel.
// One block per (b, y, dy): 2304 blocks, 192 threads = (x:64, dx-group g:3),
// each thread produces 3 consecutive dx taps.
// out = relu(rawdot(f1[:,y,x], f2[:,y2,x2]) * rsqrt(||f1||^2+eps) * rsqrt(||f2||^2+eps))
__global__ __launch_bounds__(192) void corr_kernel(const float* __restrict__ f1,
                                                   const float* __restrict__ f2,
                                                   float* __restrict__ out) {
    __shared__ float ldsB[CC * 72];   // [c][72]; cols 0..3 & 68..71 zero pad (18 KB)
    __shared__ float ldsS[72];        // inv-norm of f2 per padded column

    const int tid = threadIdx.x;
    const int bid = blockIdx.x;
    const int dy = bid % PATCH;          // fastest
    const int y  = (bid / PATCH) & 63;
    const int b  = bid / (PATCH * HH);
    const int x  = tid & 63;
    const int g  = tid >> 6;             // 0..2
    const int gy2 = y + dy - HALF;

    float* ob = out + b * P2 * HW + y * WW + x;

    if ((unsigned)gy2 >= HH) {
#pragma unroll
        for (int j = 0; j < 3; ++j)
            ob[(dy * PATCH + g * 3 + j) * HW] = 0.f;
        return;
    }

    const float* f1r = f1 + b * CC * HW + y * WW;     // + c*HW + x
    const float* f2r = f2 + b * CC * HW + gy2 * WW;   // + c*HW

    // stage raw f2 row (all channels) as [c][72], zero pads, float4 loads
    for (int i = tid; i < CC * 16; i += 192) {
        int c = i >> 4, k = i & 15;
        float4 v = *(const float4*)(f2r + c * HW + k * 4);
        *(float4*)(&ldsB[c * 72 + 4 + k * 4]) = v;
    }
    for (int j = tid; j < CC * 8; j += 192) {
        int c = j >> 3, e = j & 7;
        ldsB[c * 72 + (e < 4 ? e : e + 64)] = 0.f;   // cols 0..3 and 68..71
    }
    __syncthreads();

    // f2 column inverse norms (includes pad cols: rsqrt(eps), harmless since acc==0)
    if (tid < 72) {
        v2f ss = {0.f, 0.f};
#pragma unroll
        for (int c = 0; c < CC; c += 2) {
            v2f v = {ldsB[c * 72 + tid], ldsB[(c + 1) * 72 + tid]};  // ds_read2
            ss += v * v;
        }
        ldsS[tid] = rsqrtf(ss.x + ss.y + 1e-6f);
    }

    // main loop: channel pairs, packed fp32 FMA
    v2f acc0 = {0.f, 0.f}, acc1 = {0.f, 0.f}, acc2 = {0.f, 0.f};
    v2f sacc = {0.f, 0.f};
    const int boff = x + g * 3;   // padded col of tap0
#pragma unroll
    for (int c0 = 0; c0 < CC; c0 += 16) {
        float a[16];
#pragma unroll
        for (int j = 0; j < 16; ++j) a[j] = f1r[(c0 + j) * HW + x];
#pragma unroll
        for (int j = 0; j < 16; j += 2) {
            v2f a2 = {a[j], a[j + 1]};
            const float* br = &ldsB[(c0 + j) * 72 + boff];
            v2f b0 = {br[0], br[72]};
            v2f b1 = {br[1], br[73]};
            v2f b2 = {br[2], br[74]};
            acc0 += a2 * b0;
            acc1 += a2 * b1;
            acc2 += a2 * b2;
            sacc += a2 * a2;
        }
    }
    __syncthreads();

    const float s1 = rsqrtf(sacc.x + sacc.y + 1e-6f);
    float accs[3] = {acc0.x + acc0.y, acc1.x + acc1.y, acc2.x + acc2.y};
#pragma unroll
    for (int j = 0; j < 3; ++j) {
        int dx = g * 3 + j;
        float s2 = ldsS[boff + j];
        ob[(dy * PATCH + dx) * HW] = fmaxf(accs[j] * s1 * s2, 0.f);
    }
}

extern "C" void kernel_launch(void* const* d_in, const int* in_sizes, int n_in,
                              void* d_out, int out_size, void* d_ws, size_t ws_size,
                              hipStream_t stream) {
    const float* f1 = (const float*)d_in[0];
    const float* f2 = (const float*)d_in[1];
    float* out = (float*)d_out;
    (void)d_ws; (void)ws_size;

    corr_kernel<<<BB * HH * PATCH, 192, 0, stream>>>(f1, f2, out);
}